// Round 7
// baseline (72.059 us; speedup 1.0000x reference)
//
#include <hip/hip_runtime.h>
#include <hip/hip_fp16.h>
#include <math.h>

#define B_ 16
#define F_ 256
#define T_ 2048
#define K_ 20
#define OUTK 21
#define NPAIR 11
#define CTOFF (B_ * T_ * F_ * 2)   // byte offset of cth table relative to zth (16 MB)

typedef _Float16 half2v __attribute__((ext_vector_type(2)));

__device__ __forceinline__ half2v h2(unsigned u) { return __builtin_bit_cast(half2v, u); }
__device__ __forceinline__ float fdot2f(unsigned a, unsigned b, float c) {
#if __has_builtin(__builtin_amdgcn_fdot2)
    return __builtin_amdgcn_fdot2(h2(a), h2(b), c, false);
#else
    half2v x = h2(a), y = h2(b);
    return fmaf((float)x[1], (float)y[1], fmaf((float)x[0], (float)y[0], c));
#endif
}

// Transpose z [F][T] / c [F][T+1] (drop col 0) -> f16 [T][F] per batch,
// plus per-column sqrt(sum of squares) in fp32 (exact, from fp32 source).
__global__ __launch_bounds__(256) void transpose_norm2_kernel(
    const float* __restrict__ z, const float* __restrict__ c,
    ushort* __restrict__ zth, ushort* __restrict__ cth,
    float* __restrict__ snz, float* __restrict__ snc)
{
    __shared__ float tile[256][33];  // 256 f x 32 t, +1 pad
    int which = blockIdx.z;
    const float* src = which ? c : z;
    ushort* dst = which ? cth : zth;
    float* nrm = which ? snc : snz;
    int Lsrc = which ? (T_ + 1) : T_;
    int co   = which;                 // c drops the start token

    int b  = blockIdx.y;
    int t0 = blockIdx.x * 32;
    const float* srcb = src + (size_t)b * F_ * Lsrc;
    int tl = threadIdx.x & 31;   // t within tile
    int fl = threadIdx.x >> 5;   // 0..7
#pragma unroll
    for (int i = 0; i < 32; ++i) {
        int f = i * 8 + fl;
        tile[f][tl] = srcb[(size_t)f * Lsrc + (t0 + tl + co)];
    }
    __syncthreads();
    // write phase: pack 2 adjacent f into one uint; 128 lanes cover a row, 2 rows/iter
    int l   = threadIdx.x & 127;
    int rhi = threadIdx.x >> 7;
#pragma unroll
    for (int j2 = 0; j2 < 16; ++j2) {
        int row = j2 * 2 + rhi;
        float a  = tile[2 * l][row];
        float bb = tile[2 * l + 1][row];
        unsigned u = ((unsigned)__half_as_ushort(__float2half(bb)) << 16)
                   |  (unsigned)__half_as_ushort(__float2half(a));
        unsigned* drow = (unsigned*)(dst + ((size_t)b * T_ + t0 + row) * F_);
        drow[l] = u;
    }
    if (threadIdx.x < 32) {
        float s = 0.f;
#pragma unroll 8
        for (int f = 0; f < 256; ++f) { float v = tile[f][threadIdx.x]; s += v * v; }
        nrm[b * T_ + t0 + threadIdx.x] = sqrtf(s);
    }
}

// Sum within each 32-lane half (pure VALU DPP). Valid in lane 31 (lo) / 63 (hi).
__device__ __forceinline__ float dpp_half_sum(float x) {
    x += __int_as_float(__builtin_amdgcn_mov_dpp(__float_as_int(x), 0x111, 0xF, 0xF, true)); // row_shr:1
    x += __int_as_float(__builtin_amdgcn_mov_dpp(__float_as_int(x), 0x112, 0xF, 0xF, true)); // row_shr:2
    x += __int_as_float(__builtin_amdgcn_mov_dpp(__float_as_int(x), 0x114, 0xF, 0xF, true)); // row_shr:4
    x += __int_as_float(__builtin_amdgcn_mov_dpp(__float_as_int(x), 0x118, 0xF, 0xF, true)); // row_shr:8
    x += __int_as_float(__builtin_amdgcn_mov_dpp(__float_as_int(x), 0x142, 0xF, 0xF, true)); // row_bcast:15
    return x;
}

// One 64-lane wave per (b,t). Targets processed two-per-wave-load (uint4:
// lanes 0-31 = target 2p, lanes 32-63 = target 2p+1). All 11 pair loads are
// issued before a sched_barrier(0) ->真 prefetch. Parallel lane-k epilogue.
__global__ __launch_bounds__(256) void sim_kernel(
    const ushort* __restrict__ zth, const ushort* __restrict__ cth,
    const float* __restrict__ snz, const float* __restrict__ snc,
    const int* __restrict__ inds, float* __restrict__ out)
{
    __shared__ float sd[128];                         // 4 waves x 32 slots
    int i = blockIdx.x;                               // 8192 blocks, 4 waves each
    int b = (i & 7) | ((i >= 4096) ? 8 : 0);          // batch b on XCD b&7 (L2-resident table)
    int wid = threadIdx.x >> 6;
    int t = (((i >> 3) & 511) << 2) + wid;
    int lane = threadIdx.x & 63;
    int hl = lane & 31;                               // pos within half
    int hi = lane >> 5;                               // which half
    int bt = __builtin_amdgcn_readfirstlane((b << 11) + t);

    // epilogue gathers issued FIRST (hidden under the big row loads):
    // lane k in 1..20 reloads its negative index; then its target norm.
    const int* myinds = inds + bt * K_;
    int lm1 = (lane >= 1 && lane <= 20) ? (lane - 1) : 0;
    int myidx = myinds[lm1];
    const float* np = (lane == 0) ? (snc + bt)
                    : ((lane <= 20) ? (snz + ((b << 11) + myidx)) : (snz + bt));
    float stn = *np;
    float szn = snz[bt];                              // uniform

    const uint4* zrow = (const uint4*)(zth + (size_t)bt * F_);
    const uint4* crow = (const uint4*)(cth + (size_t)bt * F_);
    uint4 zv = zrow[hl];
    uint4 cv = crow[hl];

    // scalar byte-offsets for the 21 target rows (+1 pad), in one table space
    unsigned offs[OUTK + 1];
    offs[0] = (unsigned)CTOFF + (unsigned)bt * 512u;  // positive: c row
#pragma unroll
    for (int k = 1; k <= K_; ++k) {
        int idx = __builtin_amdgcn_readfirstlane(myinds[k - 1]);
        offs[k] = (unsigned)((b << 11) + idx) * 512u;
    }
    offs[OUTK] = offs[K_];                            // pad for odd count

    unsigned laneoff = (unsigned)hl * 16u;
    const char* tbl = (const char*)zth;

    uint4 tv[NPAIR];
#pragma unroll
    for (int p = 0; p < NPAIR; ++p) {
        unsigned off = (hi ? offs[2 * p + 1] : offs[2 * p]) + laneoff;
        tv[p] = *(const uint4*)(tbl + off);
    }

    // hard scheduler fence: nothing crosses -> all loads stay issued up-front
    __builtin_amdgcn_sched_barrier(0);

    float dz[NPAIR];
#pragma unroll
    for (int p = 0; p < NPAIR; ++p) {
        float d = fdot2f(tv[p].x, zv.x, 0.f);
        d = fdot2f(tv[p].y, zv.y, d);
        d = fdot2f(tv[p].z, zv.z, d);
        d = fdot2f(tv[p].w, zv.w, d);
        dz[p] = d;
    }

    // exact neg_is_pos: cheap 1-uint screen, uniform-branch full recheck (rare)
    unsigned mb = 0;
#pragma unroll
    for (int p = 0; p < NPAIR; ++p) {
        unsigned long long ball = __ballot(tv[p].x == cv.x);
        unsigned blo = (unsigned)ball, bhi = (unsigned)(ball >> 32);
        if (blo == 0xFFFFFFFFu || bhi == 0xFFFFFFFFu) {
            bool full = (tv[p].x == cv.x) && (tv[p].y == cv.y) &&
                        (tv[p].z == cv.z) && (tv[p].w == cv.w);
            unsigned long long b2 = __ballot(full);
            if ((unsigned)b2 == 0xFFFFFFFFu)          mb |= 1u << (2 * p);
            if ((unsigned)(b2 >> 32) == 0xFFFFFFFFu)  mb |= 1u << (2 * p + 1);
        }
    }
    mb &= ~1u;                                        // k=0 (positive) never masked

#pragma unroll
    for (int p = 0; p < NPAIR; ++p) dz[p] = dpp_half_sum(dz[p]);

    // collect: lanes 31/63 deposit pair results (same wave -> in-order DS, no barrier)
    int slotbase = wid * 32 + hi;
    if (hl == 31) {
#pragma unroll
        for (int p = 0; p < NPAIR; ++p) sd[slotbase + 2 * p] = dz[p];
    }

    // parallel epilogue: lane k finishes output k
    if (lane < OUTK) {
        float d = sd[wid * 32 + lane];
        float den = fmaxf(szn * stn, 1e-8f);
        float v = (d / den) * 2.0f;                   // / TEMP, TEMP = 0.5
        if ((mb >> lane) & 1u) v = -INFINITY;
        out[(size_t)bt * OUTK + lane] = v;
    }
}

extern "C" void kernel_launch(void* const* d_in, const int* in_sizes, int n_in,
                              void* d_out, int out_size, void* d_ws, size_t ws_size,
                              hipStream_t stream)
{
    const float* z    = (const float*)d_in[0];
    const float* c    = (const float*)d_in[1];
    const int*   inds = (const int*)d_in[2];
    float* out = (float*)d_out;

    char* ws = (char*)d_ws;
    size_t th_bytes = (size_t)B_ * T_ * F_ * sizeof(ushort);  // 16 MB
    ushort* zth = (ushort*)ws;
    ushort* cth = (ushort*)(ws + th_bytes);                   // zth + CTOFF
    float*  snz = (float*)(ws + 2 * th_bytes);
    float*  snc = snz + B_ * T_;

    dim3 tb(256), tg(T_ / 32, B_, 2);
    transpose_norm2_kernel<<<tg, tb, 0, stream>>>(z, c, zth, cth, snz, snc);
    sim_kernel<<<dim3(B_ * T_ / 4), dim3(256), 0, stream>>>(zth, cth, snz, snc, inds, out);
}

// Round 8
// 47.466 us; speedup vs baseline: 1.5181x; 1.5181x over previous
//
#include <hip/hip_runtime.h>
#include <hip/hip_fp16.h>
#include <math.h>

#define B_ 16
#define F_ 256
#define T_ 2048
#define K_ 20
#define OUTK 21
#define NPAIR 11
#define CTOFF (B_ * T_ * F_ * 2)   // byte offset of cth table relative to zth (16 MB)

typedef _Float16 half2v __attribute__((ext_vector_type(2)));

__device__ __forceinline__ half2v h2(unsigned u) { return __builtin_bit_cast(half2v, u); }
__device__ __forceinline__ float fdot2f(unsigned a, unsigned b, float c) {
#if __has_builtin(__builtin_amdgcn_fdot2)
    return __builtin_amdgcn_fdot2(h2(a), h2(b), c, false);
#else
    half2v x = h2(a), y = h2(b);
    return fmaf((float)x[1], (float)y[1], fmaf((float)x[0], (float)y[0], c));
#endif
}

// Transpose z [F][T] / c [F][T+1] (drop col 0) -> f16 [T][F] per batch,
// plus per-column sqrt(sum of squares) in fp32 (exact, from fp32 source).
__global__ __launch_bounds__(256) void transpose_norm2_kernel(
    const float* __restrict__ z, const float* __restrict__ c,
    ushort* __restrict__ zth, ushort* __restrict__ cth,
    float* __restrict__ snz, float* __restrict__ snc)
{
    __shared__ float tile[256][33];  // 256 f x 32 t, +1 pad
    int which = blockIdx.z;
    const float* src = which ? c : z;
    ushort* dst = which ? cth : zth;
    float* nrm = which ? snc : snz;
    int Lsrc = which ? (T_ + 1) : T_;
    int co   = which;                 // c drops the start token

    int b  = blockIdx.y;
    int t0 = blockIdx.x * 32;
    const float* srcb = src + (size_t)b * F_ * Lsrc;
    int tl = threadIdx.x & 31;   // t within tile
    int fl = threadIdx.x >> 5;   // 0..7
#pragma unroll
    for (int i = 0; i < 32; ++i) {
        int f = i * 8 + fl;
        tile[f][tl] = srcb[(size_t)f * Lsrc + (t0 + tl + co)];
    }
    __syncthreads();
    // write phase: pack 2 adjacent f into one uint; 128 lanes cover a row, 2 rows/iter
    int l   = threadIdx.x & 127;
    int rhi = threadIdx.x >> 7;
#pragma unroll
    for (int j2 = 0; j2 < 16; ++j2) {
        int row = j2 * 2 + rhi;
        float a  = tile[2 * l][row];
        float bb = tile[2 * l + 1][row];
        unsigned u = ((unsigned)__half_as_ushort(__float2half(bb)) << 16)
                   |  (unsigned)__half_as_ushort(__float2half(a));
        unsigned* drow = (unsigned*)(dst + ((size_t)b * T_ + t0 + row) * F_);
        drow[l] = u;
    }
    if (threadIdx.x < 32) {
        float s = 0.f;
#pragma unroll 8
        for (int f = 0; f < 256; ++f) { float v = tile[f][threadIdx.x]; s += v * v; }
        nrm[b * T_ + t0 + threadIdx.x] = sqrtf(s);
    }
}

// Sum within each 32-lane half (pure VALU DPP). Valid in lane 31 (lo) / 63 (hi).
__device__ __forceinline__ float dpp_half_sum(float x) {
    x += __int_as_float(__builtin_amdgcn_mov_dpp(__float_as_int(x), 0x111, 0xF, 0xF, true)); // row_shr:1
    x += __int_as_float(__builtin_amdgcn_mov_dpp(__float_as_int(x), 0x112, 0xF, 0xF, true)); // row_shr:2
    x += __int_as_float(__builtin_amdgcn_mov_dpp(__float_as_int(x), 0x114, 0xF, 0xF, true)); // row_shr:4
    x += __int_as_float(__builtin_amdgcn_mov_dpp(__float_as_int(x), 0x118, 0xF, 0xF, true)); // row_shr:8
    x += __int_as_float(__builtin_amdgcn_mov_dpp(__float_as_int(x), 0x142, 0xF, 0xF, true)); // row_bcast:15
    return x;
}

// One 64-lane wave per (b,t). Two targets per wave-load (uint4: lanes 0-31 =
// target 2p, lanes 32-63 = target 2p+1). Offsets via inline readlane (pure
// SGPR, NO array -> no scratch). All 11 loads fenced in flight by
// sched_barrier(0). Parallel lane-k epilogue via tiny LDS.
__global__ __launch_bounds__(256, 4) void sim_kernel(
    const ushort* __restrict__ zth, const ushort* __restrict__ cth,
    const float* __restrict__ snz, const float* __restrict__ snc,
    const int* __restrict__ inds, float* __restrict__ out)
{
    __shared__ float sd[128];                         // 4 waves x 32 slots
    int i = blockIdx.x;                               // 8192 blocks, 4 waves each
    int b = (i & 7) | ((i >= 4096) ? 8 : 0);          // batch b on XCD b&7 (L2-resident table)
    int wid = threadIdx.x >> 6;
    int t = (((i >> 3) & 511) << 2) + wid;
    int lane = threadIdx.x & 63;
    int hl = lane & 31;                               // pos within half
    int hi = lane >> 5;                               // which half
    int bt = __builtin_amdgcn_readfirstlane((b << 11) + t);

    const int* myinds = inds + bt * K_;
    // lane k holds inds[k] (k<20) for readlane-based scalar offsets
    int idxv = myinds[(lane < K_) ? lane : 0];
    // epilogue norm gather (lane k -> norm of its target), issued early
    int lm1 = (lane >= 1 && lane <= K_) ? (lane - 1) : 0;
    int myidx = myinds[lm1];
    const float* np = (lane == 0) ? (snc + bt)
                    : ((lane <= K_) ? (snz + ((b << 11) + myidx)) : (snz + bt));
    float stn = *np;
    float szn = snz[bt];                              // uniform

    const uint4* zrow = (const uint4*)(zth + (size_t)bt * F_);
    const uint4* crow = (const uint4*)(cth + (size_t)bt * F_);
    uint4 zv = zrow[hl];
    uint4 cv = crow[hl];

    const char* tbl = (const char*)zth;
    unsigned base_z  = (unsigned)(b << 11) * 512u;    // batch base byte offset
    unsigned laneoff = (unsigned)hl * 16u;

    uint4 tv[NPAIR];
    {   // pair 0: lo = c row (positive), hi = inds[0]
        unsigned olo = (unsigned)CTOFF + (unsigned)bt * 512u;
        unsigned ohi = base_z + (unsigned)__builtin_amdgcn_readlane(idxv, 0) * 512u;
        tv[0] = *(const uint4*)(tbl + ((hi ? ohi : olo) + laneoff));
    }
#pragma unroll
    for (int p = 1; p < NPAIR; ++p) {
        // target k=2p -> inds[2p-1]; k=2p+1 -> inds[2p] (p=10 hi pads with inds[19])
        unsigned ilo = (unsigned)__builtin_amdgcn_readlane(idxv, 2 * p - 1);
        unsigned ihi = (unsigned)__builtin_amdgcn_readlane(idxv, (p == 10) ? 19 : 2 * p);
        unsigned off = base_z + (hi ? ihi : ilo) * 512u + laneoff;
        tv[p] = *(const uint4*)(tbl + off);
    }

    // hard scheduler fence: nothing crosses -> all 11 loads stay issued up-front
    __builtin_amdgcn_sched_barrier(0);

    float dz[NPAIR];
#pragma unroll
    for (int p = 0; p < NPAIR; ++p) {
        float d = fdot2f(tv[p].x, zv.x, 0.f);
        d = fdot2f(tv[p].y, zv.y, d);
        d = fdot2f(tv[p].z, zv.z, d);
        d = fdot2f(tv[p].w, zv.w, d);
        dz[p] = d;
    }

    // exact neg_is_pos: cheap 1-uint screen, uniform-branch full recheck (rare)
    unsigned mb = 0;
#pragma unroll
    for (int p = 0; p < NPAIR; ++p) {
        unsigned long long ball = __ballot(tv[p].x == cv.x);
        unsigned blo = (unsigned)ball, bhi = (unsigned)(ball >> 32);
        if (blo == 0xFFFFFFFFu || bhi == 0xFFFFFFFFu) {
            bool full = (tv[p].x == cv.x) && (tv[p].y == cv.y) &&
                        (tv[p].z == cv.z) && (tv[p].w == cv.w);
            unsigned long long b2 = __ballot(full);
            if ((unsigned)b2 == 0xFFFFFFFFu)          mb |= 1u << (2 * p);
            if ((unsigned)(b2 >> 32) == 0xFFFFFFFFu)  mb |= 1u << (2 * p + 1);
        }
    }
    mb &= ~1u;                                        // k=0 (positive) never masked

#pragma unroll
    for (int p = 0; p < NPAIR; ++p) dz[p] = dpp_half_sum(dz[p]);

    // collect: lanes 31/63 deposit pair results (same wave -> in-order DS, no barrier)
    int slotbase = wid * 32 + hi;
    if (hl == 31) {
#pragma unroll
        for (int p = 0; p < NPAIR; ++p) sd[slotbase + 2 * p] = dz[p];
    }

    // parallel epilogue: lane k finishes output k
    if (lane < OUTK) {
        float d = sd[wid * 32 + lane];
        float den = fmaxf(szn * stn, 1e-8f);
        float v = (d / den) * 2.0f;                   // / TEMP, TEMP = 0.5
        if ((mb >> lane) & 1u) v = -INFINITY;
        out[(size_t)bt * OUTK + lane] = v;
    }
}

extern "C" void kernel_launch(void* const* d_in, const int* in_sizes, int n_in,
                              void* d_out, int out_size, void* d_ws, size_t ws_size,
                              hipStream_t stream)
{
    const float* z    = (const float*)d_in[0];
    const float* c    = (const float*)d_in[1];
    const int*   inds = (const int*)d_in[2];
    float* out = (float*)d_out;

    char* ws = (char*)d_ws;
    size_t th_bytes = (size_t)B_ * T_ * F_ * sizeof(ushort);  // 16 MB
    ushort* zth = (ushort*)ws;
    ushort* cth = (ushort*)(ws + th_bytes);                   // zth + CTOFF
    float*  snz = (float*)(ws + 2 * th_bytes);
    float*  snc = snz + B_ * T_;

    dim3 tb(256), tg(T_ / 32, B_, 2);
    transpose_norm2_kernel<<<tg, tb, 0, stream>>>(z, c, zth, cth, snz, snc);
    sim_kernel<<<dim3(B_ * T_ / 4), dim3(256), 0, stream>>>(zth, cth, snz, snc, inds, out);
}